// Round 13
// baseline (869.061 us; speedup 1.0000x reference)
//
#include <hip/hip_runtime.h>

// LSTMNet: 2-layer LSTM (in=1, hid=32) + linear(32->1), B=2048, T=1024, fp32.
// R13: v_pk_fma_f32 formulation. R12's A/B proved both fdot2 builtins lower
// to 2x v_fma_mix_f32 (issue rate unchanged at ~763 cyc/wave-step) -- the
// packed-f16 dot is a mirage on gfx950. v_pk_fma_f32 (CDNA2+ VOP3P) does
// 2 EXACT fp32 MACs per instruction; clang emits it for <2 x float> fma
// (__builtin_elementwise_fma). Weights return to fp32 (192 VGPRs): accuracy
// becomes exact-matvec (absmax ~1e-5 expected), and the 96 weight-pairs per
// step cost 96 instrs instead of ~192.
// Gates accumulate packed over even/odd k; 3-add horizontal reduce at end.
// h state lives in fp32 LDS rings (wave-uniform float4 broadcast reads);
// per-step h1 also goes to hstore for the chunk-hoisted head (R7 technique).
// One wave per batch row; 64 lanes = 32 units x 2 halves (i,f | g,o).
// VGPR target ~220 -> 2 waves/SIMD at the 256-reg tier (waves_per_eu(2,2)).

typedef float f2 __attribute__((ext_vector_type(2)));
typedef float f4 __attribute__((ext_vector_type(4)));

constexpr int BATCH = 2048;
constexpr int TLEN  = 1024;
constexpr int HID   = 32;
constexpr float L2E = 1.44269504088896f;   // log2(e)

union F4U { f4 v; f2 p[2]; };

static __device__ __forceinline__ float rcp_f(float v){ return __builtin_amdgcn_rcpf(v); }
static __device__ __forceinline__ float exp2_f(float v){ return __builtin_amdgcn_exp2f(v); }
static __device__ __forceinline__ float bcastf(float v, int k){
    return __int_as_float(__builtin_amdgcn_readlane(__float_as_int(v), k));
}
static __device__ __forceinline__ f2 fma2(f2 a, f2 b, f2 c){
    return __builtin_elementwise_fma(a, b, c);   // -> v_pk_fma_f32
}
static __device__ __forceinline__ float xchg32(float v, int xaddr){
    return __int_as_float(__builtin_amdgcn_ds_bpermute(xaddr, __float_as_int(v)));
}

__global__ void __launch_bounds__(256) __attribute__((amdgpu_waves_per_eu(2, 2)))
lstm2_v13(const float* __restrict__ x,
          const float* __restrict__ Wih0, const float* __restrict__ Whh0,
          const float* __restrict__ bih0, const float* __restrict__ bhh0,
          const float* __restrict__ Wih1, const float* __restrict__ Whh1,
          const float* __restrict__ bih1, const float* __restrict__ bhh1,
          const float* __restrict__ Wlin, const float* __restrict__ blin,
          float* __restrict__ out)
{
    const int tid  = threadIdx.x;
    const int lane = tid & 63;
    const int w    = tid >> 6;                 // wave within block (0..3)
    const int b    = blockIdx.x * 4 + w;       // batch row
    const int j    = lane & 31;
    const int hi   = lane >> 5;                // 0: i,f rows   1: g,o rows
    const int rowA = hi * 64 + j;              // i (hi=0) / g (hi=1)
    const int rowB = rowA + 32;                // f (hi=0) / o (hi=1)
    const int xaddr = (lane ^ 32) << 2;        // bpermute byte addr

    __shared__ alignas(16) float hb0[4][32];          // h0 ring (per wave)
    __shared__ alignas(16) float hb1[4][32];          // h1 ring (per wave)
    __shared__ alignas(16) float hstore[4][64][36];   // h1 per step (head), 144B stride
    __shared__ alignas(16) float wls[32];             // Wlin copy

    // wave-local LDS init (both halves write identical values; no barriers)
    hb0[w][j] = 0.0f;
    hb1[w][j] = 0.0f;
    wls[j] = Wlin[j];

    // ---- per-lane weights as fp32 pairs (192 VGPRs) ----
    f2 wA0[16], wB0[16], iA1[16], iB1[16], hA1[16], hB1[16];
    #pragma unroll
    for (int m = 0; m < 16; ++m){
        wA0[m] = *(const f2*)&Whh0[rowA * HID + 2*m];
        wB0[m] = *(const f2*)&Whh0[rowB * HID + 2*m];
        iA1[m] = *(const f2*)&Wih1[rowA * HID + 2*m];
        iB1[m] = *(const f2*)&Wih1[rowB * HID + 2*m];
        hA1[m] = *(const f2*)&Whh1[rowA * HID + 2*m];
        hB1[m] = *(const f2*)&Whh1[rowB * HID + 2*m];
    }
    const float wa0 = Wih0[rowA];
    const float wb0 = Wih0[rowB];
    const float ba0 = bih0[rowA] + bhh0[rowA];
    const float bb0 = bih0[rowB] + bhh0[rowB];
    const float ba1 = bih1[rowA] + bhh1[rowA];
    const float bb1 = bih1[rowB] + bhh1[rowB];
    const float bl  = blin[0];

    // act-"a" selector: half0 -> sigmoid, half1 -> tanh (=2*sigm(2x)-1)
    const float kA = hi ? (-2.0f * L2E) : (-L2E);
    const float mA = hi ?  2.0f : 1.0f;
    const float cA = hi ? -1.0f : 0.0f;

    float c0 = 0.0f, c1 = 0.0f;

    const float* xrow = x   + (size_t)b * TLEN;
    float*       orow = out + (size_t)b * TLEN;

    const f4* h0v = (const f4*)&hb0[w][0];
    const f4* h1v = (const f4*)&hb1[w][0];

    for (int tc = 0; tc < TLEN / 64; ++tc){
        const float xchunk = xrow[tc * 64 + lane];   // coalesced, 64 steps

        for (int tt = 0; tt < 64; ++tt){
            const float xt = bcastf(xchunk, tt);

            // ========= layer 0: g = Whh0*h0_prev + Wih0*x + b =========
            f2 aA  = {__builtin_fmaf(wa0, xt, ba0), 0.0f};
            f2 aB  = {__builtin_fmaf(wb0, xt, bb0), 0.0f};
            f2 aA2 = {0.0f, 0.0f}, aB2 = {0.0f, 0.0f};
            #pragma unroll
            for (int r = 0; r < 8; ++r){
                F4U hh; hh.v = h0v[r];               // broadcast read (h0_prev)
                aA  = fma2(wA0[2*r],   hh.p[0], aA );
                aB  = fma2(wB0[2*r],   hh.p[0], aB );
                aA2 = fma2(wA0[2*r+1], hh.p[1], aA2);
                aB2 = fma2(wB0[2*r+1], hh.p[1], aB2);
            }
            const float ga = (aA.x + aA2.x) + (aA.y + aA2.y);
            const float gb = (aB.x + aB2.x) + (aB.y + aB2.y);

            float act_a = __builtin_fmaf(mA, rcp_f(1.0f + exp2_f(ga * kA)), cA);
            float act_b = rcp_f(1.0f + exp2_f(gb * (-L2E)));
            const float oa = xchg32(act_a, xaddr);
            const float ob = xchg32(act_b, xaddr);
            {
                const float fsel = hi ? ob : act_b;
                const float osel = hi ? act_b : ob;
                c0 = __builtin_fmaf(fsel, c0, act_a * oa);
                const float t0 = __builtin_fmaf(2.0f,
                        rcp_f(1.0f + exp2_f(c0 * (-2.0f * L2E))), -1.0f);
                const float h0 = osel * t0;
                hb0[w][j] = h0;                      // ds_write_b32 (both halves same)
            }

            // ========= layer 1: g = Wih1*h0_new + Whh1*h1_prev + b =========
            f2 pA  = {ba1, 0.0f}, pB = {bb1, 0.0f};
            f2 pA2 = {0.0f, 0.0f}, pB2 = {0.0f, 0.0f};
            #pragma unroll
            for (int r = 0; r < 8; ++r){
                F4U hn; hn.v = h0v[r];               // h0_NEW (after write, own-wave order)
                F4U ho; ho.v = h1v[r];               // h1_prev
                pA  = fma2(iA1[2*r],   hn.p[0], pA );
                pB  = fma2(iB1[2*r],   hn.p[0], pB );
                pA2 = fma2(iA1[2*r+1], hn.p[1], pA2);
                pB2 = fma2(iB1[2*r+1], hn.p[1], pB2);
                pA  = fma2(hA1[2*r],   ho.p[0], pA );
                pB  = fma2(hB1[2*r],   ho.p[0], pB );
                pA2 = fma2(hA1[2*r+1], ho.p[1], pA2);
                pB2 = fma2(hB1[2*r+1], ho.p[1], pB2);
            }
            const float g1a = (pA.x + pA2.x) + (pA.y + pA2.y);
            const float g1b = (pB.x + pB2.x) + (pB.y + pB2.y);

            float act_a1 = __builtin_fmaf(mA, rcp_f(1.0f + exp2_f(g1a * kA)), cA);
            float act_b1 = rcp_f(1.0f + exp2_f(g1b * (-L2E)));
            const float oa1 = xchg32(act_a1, xaddr);
            const float ob1 = xchg32(act_b1, xaddr);
            {
                const float fsel = hi ? ob1 : act_b1;
                const float osel = hi ? act_b1 : ob1;
                c1 = __builtin_fmaf(fsel, c1, act_a1 * oa1);
                const float t1 = __builtin_fmaf(2.0f,
                        rcp_f(1.0f + exp2_f(c1 * (-2.0f * L2E))), -1.0f);
                const float h1 = osel * t1;
                hb1[w][j] = h1;                      // recurrence ring
                hstore[w][tt][j] = h1;               // per-step slot for head
            }
        }

        // ========= head for the whole chunk: lane t -> y[t] =========
        {
            const f4* hv = (const f4*)&hstore[w][lane][0];
            const f4* wv = (const f4*)&wls[0];
            f2 y = {bl, 0.0f}, y2 = {0.0f, 0.0f};
            #pragma unroll
            for (int r = 0; r < 8; ++r){
                F4U hh; hh.v = hv[r];
                F4U ww; ww.v = wv[r];
                y  = fma2(ww.p[0], hh.p[0], y );
                y2 = fma2(ww.p[1], hh.p[1], y2);
            }
            orow[tc * 64 + lane] = (y.x + y2.x) + (y.y + y2.y);  // coalesced
        }
    }
}

extern "C" void kernel_launch(void* const* d_in, const int* in_sizes, int n_in,
                              void* d_out, int out_size, void* d_ws, size_t ws_size,
                              hipStream_t stream) {
    const float* x    = (const float*)d_in[0];
    const float* Wih0 = (const float*)d_in[1];
    const float* Whh0 = (const float*)d_in[2];
    const float* bih0 = (const float*)d_in[3];
    const float* bhh0 = (const float*)d_in[4];
    const float* Wih1 = (const float*)d_in[5];
    const float* Whh1 = (const float*)d_in[6];
    const float* bih1 = (const float*)d_in[7];
    const float* bhh1 = (const float*)d_in[8];
    const float* Wlin = (const float*)d_in[9];
    const float* blin = (const float*)d_in[10];
    float* outp = (float*)d_out;

    dim3 block(256);                 // 4 waves/block, 1 batch row per wave
    dim3 grid(BATCH / 4);            // 512 blocks -> 2048 waves -> 2/SIMD
    hipLaunchKernelGGL(lstm2_v13, grid, block, 0, stream,
                       x, Wih0, Whh0, bih0, bhh0, Wih1, Whh1, bih1, bhh1,
                       Wlin, blin, outp);
}